// Round 4
// baseline (100.447 us; speedup 1.0000x reference)
//
#include <hip/hip_runtime.h>

#define TPB 256

typedef __attribute__((ext_vector_type(8))) short short8;
typedef __attribute__((ext_vector_type(4))) float f32x4;

__device__ __forceinline__ unsigned f2bf_pk(float a, float b) {
  return ((__float_as_uint(a) + 0x8000u) >> 16) | ((__float_as_uint(b) + 0x8000u) & 0xffff0000u);
}
__device__ __forceinline__ float bflo(unsigned v) { return __uint_as_float(v << 16); }
__device__ __forceinline__ float bfhi(unsigned v) { return __uint_as_float(v & 0xffff0000u); }

// ---- prep: permuted bf16 A-fragment table (row permute makes each lane's
// 18x4 accumulator exactly 8 cin x 9 k for one pixel) ----------------------
__global__ void prep_kernel(const float* __restrict__ Wp, unsigned* __restrict__ Wq) {
  int idx = blockIdx.x * blockDim.x + threadIdx.x;  // 147456 u32
  if (idx >= 32 * 18 * 64 * 4) return;
  int j2   = idx & 3;
  int lane = (idx >> 2) & 63;
  int rt   = (idx >> 8) % 18;
  int o    = (idx >> 8) / 18;
  int m16 = lane & 15, kq = lane >> 4;
  int row = o * 288 + (m16 >> 2) * 72 + rt * 4 + (m16 & 3);
  const float* src = Wp + row * 32 + kq * 8 + j2 * 2;
  Wq[idx] = f2bf_pk(src[0], src[1]);
}

// ---- main: block = 64 px (one row) x 2 couts; syncless o-loop ------------
template <bool USE_WQ>
__global__ __launch_bounds__(TPB, 3) void dppc4_kernel(
    const float* __restrict__ x, const float* __restrict__ Wp,
    const float* __restrict__ bp, const unsigned* __restrict__ Wq,
    float* __restrict__ out) {
  __shared__ __align__(16) unsigned short xrow[3 * 32 * 68];  // [r][c][2+w+2], bf16
  __shared__ __align__(16) float bp_s[2 * 288];
  __shared__ __align__(16) float Wb_s[2 * 32];
  __shared__ float bias2[2];

  const int tid = threadIdx.x;
  const int bid = blockIdx.x;
  const int og  = bid & 15;     // couts og*2, og*2+1
  const int t   = bid >> 4;
  const int b   = t >> 6;
  const int h   = t & 63;

  // prelude: halo words and interior words are disjoint -> single barrier
  for (int i = tid; i < 96; i += TPB) {       // (r,c) halo words
    unsigned* row = (unsigned*)&xrow[i * 68];
    row[0] = 0;   // cols 0,1
    row[33] = 0;  // cols 66,67
  }
  for (int i = tid; i < 1536; i += TPB) {     // interior: 3*32*16 float4
    int r = i >> 9, c = (i >> 4) & 31, w4 = i & 15;
    int hh = h - 1 + r;
    unsigned* dst = (unsigned*)&xrow[(r * 32 + c) * 68 + 2 + w4 * 4];
    if ((unsigned)hh < 64u) {
      const float4 v = *(const float4*)(x + (((b * 32 + c) * 64 + hh) * 64 + w4 * 4));
      dst[0] = f2bf_pk(v.x, v.y);
      dst[1] = f2bf_pk(v.z, v.w);
    } else {
      dst[0] = 0u;
      dst[1] = 0u;
    }
  }
  for (int i = tid; i < 576; i += TPB) bp_s[i] = bp[og * 576 + i];
  if (tid < 64) Wb_s[tid] = Wp[(9216 + og * 2 + (tid >> 5)) * 32 + (tid & 31)];
  if (tid < 2) bias2[tid] = bp[9216 + og * 2 + tid];
  __syncthreads();

  const int lane = tid & 63;
  const int wv   = tid >> 6;
  const int m16  = lane & 15, kq = lane >> 4;
  const int px   = wv * 16 + m16;

  // persistent B fragment: B[k=cin=kq*8+j][n=px=m16]
  union { short8 v; unsigned short s[8]; } bf_;
#pragma unroll
  for (int j = 0; j < 8; ++j)
    bf_.s[j] = xrow[(32 + kq * 8 + j) * 68 + 2 + px];
  const short8 bfrag = bf_.v;

  // patch packed bf16 pairs: idx = c8*9+k  (my 8 cins x 9 taps at my px)
  unsigned patchp[36];
#pragma unroll
  for (int i = 0; i < 36; ++i) patchp[i] = 0;
#pragma unroll
  for (int c8 = 0; c8 < 8; ++c8)
#pragma unroll
    for (int kk = 0; kk < 9; ++kk) {
      const int kh = kk / 3, kw = kk - kh * 3;
      unsigned v = (unsigned)xrow[(kh * 32 + kq * 8 + c8) * 68 + 1 + kw + px];
      const int idx = c8 * 9 + kk;
      patchp[idx >> 1] |= (idx & 1) ? (v << 16) : v;
    }

#pragma unroll 1
  for (int oo = 0; oo < 2; ++oo) {
    const int o = og * 2 + oo;

    // phase 1: 18 MFMAs, bias folded into C-operand.
    // lane holds pred fp32 for idx=c8*9+k (cin=kq*8+c8) at px: acc[idx>>2][idx&3]
    f32x4 acc[18];
    if (USE_WQ) {
      const short8* wq = (const short8*)Wq + (o * 18) * 64 + lane;
#pragma unroll
      for (int rt = 0; rt < 18; ++rt) {
        const f32x4 bb = *(const f32x4*)&bp_s[oo * 288 + kq * 72 + rt * 4];
        acc[rt] = __builtin_amdgcn_mfma_f32_16x16x32_bf16(wq[rt * 64], bfrag, bb, 0, 0, 0);
      }
    } else {
      const float* ab = Wp + (o * 288 + (m16 >> 2) * 72 + (m16 & 3)) * 32 + kq * 8;
#pragma unroll
      for (int rt = 0; rt < 18; ++rt) {
        const float* ap = ab + rt * 4 * 32;
        float4 a0 = *(const float4*)ap;
        float4 a1 = *(const float4*)(ap + 4);
        union { short8 v; unsigned u[4]; } af;
        af.u[0] = f2bf_pk(a0.x, a0.y);
        af.u[1] = f2bf_pk(a0.z, a0.w);
        af.u[2] = f2bf_pk(a1.x, a1.y);
        af.u[3] = f2bf_pk(a1.z, a1.w);
        const f32x4 bb = *(const f32x4*)&bp_s[oo * 288 + kq * 72 + rt * 4];
        acc[rt] = __builtin_amdgcn_mfma_f32_16x16x32_bf16(af.v, bfrag, bb, 0, 0, 0);
      }
    }

    // cin-norm denominators: local partial + butterfly across kq (bits 4,5)
    float ss[9];
#pragma unroll
    for (int kk = 0; kk < 9; ++kk) ss[kk] = 0.f;
#pragma unroll
    for (int c8 = 0; c8 < 8; ++c8)
#pragma unroll
      for (int kk = 0; kk < 9; ++kk) {
        const int idx = c8 * 9 + kk;
        const float v = acc[idx >> 2][idx & 3];
        ss[kk] += v * v;
      }
#pragma unroll
    for (int kk = 0; kk < 9; ++kk) {
      float s = ss[kk];
      s += __shfl_xor(s, 16);
      s += __shfl_xor(s, 32);
      ss[kk] = rsqrtf(fmaxf(s, 1e-24f));  // == 1/max(sqrt(s),1e-12)
    }

    // k-norm + contraction + dyn-bias partials (local), then butterfly
    const f32x4 wb0 = *(const f32x4*)&Wb_s[oo * 32 + kq * 8];
    const f32x4 wb1 = *(const f32x4*)&Wb_s[oo * 32 + kq * 8 + 4];
    float oacc = 0.f;
#pragma unroll
    for (int c8 = 0; c8 < 8; ++c8) {
      float tk[9];
      float s2 = 0.f;
#pragma unroll
      for (int kk = 0; kk < 9; ++kk) {
        const int idx = c8 * 9 + kk;
        const float tv = acc[idx >> 2][idx & 3] * ss[kk];
        tk[kk] = tv;
        s2 += tv * tv;
      }
      const float r2 = rsqrtf(fmaxf(s2, 1e-24f));
      float dot = 0.f;
#pragma unroll
      for (int kk = 0; kk < 9; ++kk) {
        const int idx = c8 * 9 + kk;
        const float pv = (idx & 1) ? bfhi(patchp[idx >> 1]) : bflo(patchp[idx >> 1]);
        dot += tk[kk] * pv;
      }
      oacc += r2 * dot;
      const int idc = c8 * 9 + 4;  // center tap for dyn bias
      const float xc = (idc & 1) ? bfhi(patchp[idc >> 1]) : bflo(patchp[idc >> 1]);
      const float wbv = (c8 < 4) ? ((const float*)&wb0)[c8] : ((const float*)&wb1)[c8 - 4];
      oacc += wbv * xc;
    }
    oacc += __shfl_xor(oacc, 16);
    oacc += __shfl_xor(oacc, 32);
    if (kq == 0)
      out[((b * 32 + o) * 64 + h) * 64 + px] = oacc + bias2[oo];
  }
}

extern "C" void kernel_launch(void* const* d_in, const int* in_sizes, int n_in,
                              void* d_out, int out_size, void* d_ws, size_t ws_size,
                              hipStream_t stream) {
  const float* x  = (const float*)d_in[0];
  const float* Wp = (const float*)d_in[1];
  const float* bp = (const float*)d_in[2];
  float* out = (float*)d_out;
  const size_t wq_bytes = (size_t)32 * 18 * 64 * 8 * 2;  // 589824
  if (ws_size >= wq_bytes) {
    prep_kernel<<<576, 256, 0, stream>>>(Wp, (unsigned*)d_ws);
    dppc4_kernel<true><<<2048, TPB, 0, stream>>>(x, Wp, bp, (const unsigned*)d_ws, out);
  } else {
    dppc4_kernel<false><<<2048, TPB, 0, stream>>>(x, Wp, bp, nullptr, out);
  }
}

// Round 5
// 88.754 us; speedup vs baseline: 1.1318x; 1.1318x over previous
//
#include <hip/hip_runtime.h>

#define TPB 256

typedef __attribute__((ext_vector_type(8))) short short8;
typedef __attribute__((ext_vector_type(4))) float f32x4;

__device__ __forceinline__ unsigned f2bf_pk(float a, float b) {
  return ((__float_as_uint(a) + 0x8000u) >> 16) | ((__float_as_uint(b) + 0x8000u) & 0xffff0000u);
}
__device__ __forceinline__ float bflo(unsigned v) { return __uint_as_float(v << 16); }
__device__ __forceinline__ float bfhi(unsigned v) { return __uint_as_float(v & 0xffff0000u); }

// ---- prep: permuted bf16 A-fragment table (row permute makes each lane's
// 18x4 accumulator exactly 8 cin x 9 k for one pixel) ----------------------
__global__ void prep_kernel(const float* __restrict__ Wp, unsigned* __restrict__ Wq) {
  int idx = blockIdx.x * blockDim.x + threadIdx.x;  // 147456 u32
  if (idx >= 32 * 18 * 64 * 4) return;
  int j2   = idx & 3;
  int lane = (idx >> 2) & 63;
  int rt   = (idx >> 8) % 18;
  int o    = (idx >> 8) / 18;
  int m16 = lane & 15, kq = lane >> 4;
  int row = o * 288 + (m16 >> 2) * 72 + rt * 4 + (m16 & 3);
  const float* src = Wp + row * 32 + kq * 8 + j2 * 2;
  Wq[idx] = f2bf_pk(src[0], src[1]);
}

// ---- main: block = 64 px (one row) x 4 couts; syncless o-loop ------------
// og = bid & 7 also XCD-aligns blocks sharing the same Wq slice.
template <bool USE_WQ>
__global__ __launch_bounds__(TPB, 3) void dppc5_kernel(
    const float* __restrict__ x, const float* __restrict__ Wp,
    const float* __restrict__ bp, const unsigned* __restrict__ Wq,
    float* __restrict__ out) {
  __shared__ __align__(16) unsigned short xrow[3 * 32 * 68];  // [r][c][2+w+2], bf16
  __shared__ __align__(16) float bp_s[4 * 288];
  __shared__ __align__(16) float Wb_s[4 * 32];
  __shared__ float bias4[4];

  const int tid = threadIdx.x;
  const int bid = blockIdx.x;
  const int og  = bid & 7;      // couts og*4 .. og*4+3
  const int t   = bid >> 3;
  const int b   = t >> 6;
  const int h   = t & 63;

  // prelude: halo words and interior words are disjoint -> single barrier
  for (int i = tid; i < 96; i += TPB) {       // (r,c) halo words
    unsigned* row = (unsigned*)&xrow[i * 68];
    row[0] = 0;   // cols 0,1
    row[33] = 0;  // cols 66,67
  }
  for (int i = tid; i < 1536; i += TPB) {     // interior: 3*32*16 float4
    int r = i >> 9, c = (i >> 4) & 31, w4 = i & 15;
    int hh = h - 1 + r;
    unsigned* dst = (unsigned*)&xrow[(r * 32 + c) * 68 + 2 + w4 * 4];
    if ((unsigned)hh < 64u) {
      const float4 v = *(const float4*)(x + (((b * 32 + c) * 64 + hh) * 64 + w4 * 4));
      dst[0] = f2bf_pk(v.x, v.y);
      dst[1] = f2bf_pk(v.z, v.w);
    } else {
      dst[0] = 0u;
      dst[1] = 0u;
    }
  }
  for (int i = tid; i < 1152; i += TPB) bp_s[i] = bp[og * 1152 + i];
  if (tid < 128) Wb_s[tid] = Wp[(9216 + og * 4 + (tid >> 5)) * 32 + (tid & 31)];
  if (tid < 4) bias4[tid] = bp[9216 + og * 4 + tid];
  __syncthreads();

  const int lane = tid & 63;
  const int wv   = tid >> 6;
  const int m16  = lane & 15, kq = lane >> 4;
  const int px   = wv * 16 + m16;

  // persistent B fragment: B[k=cin=kq*8+j][n=px=m16]
  union { short8 v; unsigned short s[8]; } bf_;
#pragma unroll
  for (int j = 0; j < 8; ++j)
    bf_.s[j] = xrow[(32 + kq * 8 + j) * 68 + 2 + px];
  const short8 bfrag = bf_.v;

  // patch packed bf16 pairs: idx = c8*9+k  (my 8 cins x 9 taps at my px)
  unsigned patchp[36];
#pragma unroll
  for (int i = 0; i < 36; ++i) patchp[i] = 0;
#pragma unroll
  for (int c8 = 0; c8 < 8; ++c8)
#pragma unroll
    for (int kk = 0; kk < 9; ++kk) {
      const int kh = kk / 3, kw = kk - kh * 3;
      unsigned v = (unsigned)xrow[(kh * 32 + kq * 8 + c8) * 68 + 1 + kw + px];
      const int idx = c8 * 9 + kk;
      patchp[idx >> 1] |= (idx & 1) ? (v << 16) : v;
    }

#pragma unroll 1
  for (int oo = 0; oo < 4; ++oo) {
    const int o = og * 4 + oo;

    // phase 1: 18 MFMAs, predictor bias folded into C-operand.
    // lane holds pred fp32 for idx=c8*9+k (cin=kq*8+c8) at px: acc[idx>>2][idx&3]
    f32x4 acc[18];
    if (USE_WQ) {
      const short8* wq = (const short8*)Wq + (o * 18) * 64 + lane;
#pragma unroll
      for (int rt = 0; rt < 18; ++rt) {
        const f32x4 bb = *(const f32x4*)&bp_s[oo * 288 + kq * 72 + rt * 4];
        acc[rt] = __builtin_amdgcn_mfma_f32_16x16x32_bf16(wq[rt * 64], bfrag, bb, 0, 0, 0);
      }
    } else {
      const float* ab = Wp + (o * 288 + (m16 >> 2) * 72 + (m16 & 3)) * 32 + kq * 8;
#pragma unroll
      for (int rt = 0; rt < 18; ++rt) {
        const float* ap = ab + rt * 4 * 32;
        float4 a0 = *(const float4*)ap;
        float4 a1 = *(const float4*)(ap + 4);
        union { short8 v; unsigned u[4]; } af;
        af.u[0] = f2bf_pk(a0.x, a0.y);
        af.u[1] = f2bf_pk(a0.z, a0.w);
        af.u[2] = f2bf_pk(a1.x, a1.y);
        af.u[3] = f2bf_pk(a1.z, a1.w);
        const f32x4 bb = *(const f32x4*)&bp_s[oo * 288 + kq * 72 + rt * 4];
        acc[rt] = __builtin_amdgcn_mfma_f32_16x16x32_bf16(af.v, bfrag, bb, 0, 0, 0);
      }
    }

    // cin-norm denominators: local partial + butterfly across kq (bits 4,5)
    float rinv[9];
#pragma unroll
    for (int kk = 0; kk < 9; ++kk) rinv[kk] = 0.f;
#pragma unroll
    for (int c8 = 0; c8 < 8; ++c8)
#pragma unroll
      for (int kk = 0; kk < 9; ++kk) {
        const int idx = c8 * 9 + kk;
        const float v = acc[idx >> 2][idx & 3];
        rinv[kk] += v * v;
      }
#pragma unroll
    for (int kk = 0; kk < 9; ++kk) {
      float s = rinv[kk];
      s += __shfl_xor(s, 16);
      s += __shfl_xor(s, 32);
      rinv[kk] = rsqrtf(fmaxf(s, 1e-24f));  // == 1/max(sqrt(s),1e-12)
    }

    // k-norm + contraction + dyn-bias partials: s2 and dot accumulated in
    // one pass (no tk[] storage); r2 applied to dot afterwards.
    const f32x4 wb0 = *(const f32x4*)&Wb_s[oo * 32 + kq * 8];
    const f32x4 wb1 = *(const f32x4*)&Wb_s[oo * 32 + kq * 8 + 4];
    float oacc = 0.f;
#pragma unroll
    for (int c8 = 0; c8 < 8; ++c8) {
      float s2 = 0.f, dot = 0.f;
#pragma unroll
      for (int kk = 0; kk < 9; ++kk) {
        const int idx = c8 * 9 + kk;
        const float tv = acc[idx >> 2][idx & 3] * rinv[kk];
        s2 += tv * tv;
        const float pv = (idx & 1) ? bfhi(patchp[idx >> 1]) : bflo(patchp[idx >> 1]);
        dot += tv * pv;
      }
      oacc += rsqrtf(fmaxf(s2, 1e-24f)) * dot;
      const int idc = c8 * 9 + 4;  // center tap for dyn bias
      const float xc = (idc & 1) ? bfhi(patchp[idc >> 1]) : bflo(patchp[idc >> 1]);
      const float wbv = (c8 < 4) ? ((const float*)&wb0)[c8] : ((const float*)&wb1)[c8 - 4];
      oacc += wbv * xc;
    }
    oacc += __shfl_xor(oacc, 16);
    oacc += __shfl_xor(oacc, 32);
    if (kq == 0)
      out[((b * 32 + o) * 64 + h) * 64 + px] = oacc + bias4[oo];
  }
}

extern "C" void kernel_launch(void* const* d_in, const int* in_sizes, int n_in,
                              void* d_out, int out_size, void* d_ws, size_t ws_size,
                              hipStream_t stream) {
  const float* x  = (const float*)d_in[0];
  const float* Wp = (const float*)d_in[1];
  const float* bp = (const float*)d_in[2];
  float* out = (float*)d_out;
  const size_t wq_bytes = (size_t)32 * 18 * 64 * 8 * 2;  // 589824
  if (ws_size >= wq_bytes) {
    prep_kernel<<<576, 256, 0, stream>>>(Wp, (unsigned*)d_ws);
    dppc5_kernel<true><<<1024, TPB, 0, stream>>>(x, Wp, bp, (const unsigned*)d_ws, out);
  } else {
    dppc5_kernel<false><<<1024, TPB, 0, stream>>>(x, Wp, bp, nullptr, out);
  }
}

// Round 6
// 83.221 us; speedup vs baseline: 1.2070x; 1.0665x over previous
//
#include <hip/hip_runtime.h>

#define TPB 256

typedef __attribute__((ext_vector_type(8))) short short8;
typedef __attribute__((ext_vector_type(4))) float f32x4;

__device__ __forceinline__ unsigned f2bf_pk(float a, float b) {
  return ((__float_as_uint(a) + 0x8000u) >> 16) | ((__float_as_uint(b) + 0x8000u) & 0xffff0000u);
}
__device__ __forceinline__ float bflo(unsigned v) { return __uint_as_float(v << 16); }
__device__ __forceinline__ float bfhi(unsigned v) { return __uint_as_float(v & 0xffff0000u); }

// ---- prep: permuted bf16 A-fragment table (row permute makes each lane's
// 18x4 accumulator exactly 8 cin x 9 k for one pixel) ----------------------
__global__ void prep_kernel(const float* __restrict__ Wp, unsigned* __restrict__ Wq) {
  int idx = blockIdx.x * blockDim.x + threadIdx.x;  // 147456 u32
  if (idx >= 32 * 18 * 64 * 4) return;
  int j2   = idx & 3;
  int lane = (idx >> 2) & 63;
  int rt   = (idx >> 8) % 18;
  int o    = (idx >> 8) / 18;
  int m16 = lane & 15, kq = lane >> 4;
  int row = o * 288 + (m16 >> 2) * 72 + rt * 4 + (m16 & 3);
  const float* src = Wp + row * 32 + kq * 8 + j2 * 2;
  Wq[idx] = f2bf_pk(src[0], src[1]);
}

// ---- main: block = 64 px (one row) x 4 couts; syncless, software-pipelined
// o-loop: next-o Wq loads issued right after MFMAs consume current buffer,
// so L2 latency hides under the norm phase. (256,2): room for wq[18] regs.
template <bool USE_WQ>
__global__ __launch_bounds__(TPB, 2) void dppc6_kernel(
    const float* __restrict__ x, const float* __restrict__ Wp,
    const float* __restrict__ bp, const unsigned* __restrict__ Wq,
    float* __restrict__ out) {
  __shared__ __align__(16) unsigned short xrow[3 * 32 * 68];  // [r][c][2+w+2], bf16
  __shared__ __align__(16) float bp_s[4 * 288];
  __shared__ __align__(16) float Wb_s[4 * 32];
  __shared__ float bias4[4];

  const int tid = threadIdx.x;
  const int bid = blockIdx.x;
  const int og  = bid & 7;      // couts og*4 .. og*4+3
  const int t   = bid >> 3;
  const int b   = t >> 6;
  const int h   = t & 63;

  // prelude: halo words and interior words are disjoint -> single barrier
  for (int i = tid; i < 96; i += TPB) {       // (r,c) halo words
    unsigned* row = (unsigned*)&xrow[i * 68];
    row[0] = 0;   // cols 0,1
    row[33] = 0;  // cols 66,67
  }
  for (int i = tid; i < 1536; i += TPB) {     // interior: 3*32*16 float4
    int r = i >> 9, c = (i >> 4) & 31, w4 = i & 15;
    int hh = h - 1 + r;
    unsigned* dst = (unsigned*)&xrow[(r * 32 + c) * 68 + 2 + w4 * 4];
    if ((unsigned)hh < 64u) {
      const float4 v = *(const float4*)(x + (((b * 32 + c) * 64 + hh) * 64 + w4 * 4));
      dst[0] = f2bf_pk(v.x, v.y);
      dst[1] = f2bf_pk(v.z, v.w);
    } else {
      dst[0] = 0u;
      dst[1] = 0u;
    }
  }
  for (int i = tid; i < 1152; i += TPB) bp_s[i] = bp[og * 1152 + i];
  if (tid < 128) Wb_s[tid] = Wp[(9216 + og * 4 + (tid >> 5)) * 32 + (tid & 31)];
  if (tid < 4) bias4[tid] = bp[9216 + og * 4 + tid];
  __syncthreads();

  const int lane = tid & 63;
  const int wv   = tid >> 6;
  const int m16  = lane & 15, kq = lane >> 4;
  const int px   = wv * 16 + m16;

  // persistent B fragment: B[k=cin=kq*8+j][n=px=m16]
  union { short8 v; unsigned short s[8]; } bf_;
#pragma unroll
  for (int j = 0; j < 8; ++j)
    bf_.s[j] = xrow[(32 + kq * 8 + j) * 68 + 2 + px];
  const short8 bfrag = bf_.v;

  // patch packed bf16 pairs: idx = c8*9+k  (my 8 cins x 9 taps at my px)
  unsigned patchp[36];
#pragma unroll
  for (int i = 0; i < 36; ++i) patchp[i] = 0;
#pragma unroll
  for (int c8 = 0; c8 < 8; ++c8)
#pragma unroll
    for (int kk = 0; kk < 9; ++kk) {
      const int kh = kk / 3, kw = kk - kh * 3;
      unsigned v = (unsigned)xrow[(kh * 32 + kq * 8 + c8) * 68 + 1 + kw + px];
      const int idx = c8 * 9 + kk;
      patchp[idx >> 1] |= (idx & 1) ? (v << 16) : v;
    }

  // ---- preload Wq for first o into registers ----
  short8 wq[18];
  const short8* wqp = nullptr;
  if (USE_WQ) {
    wqp = (const short8*)Wq + (og * 4 * 18) * 64 + lane;
#pragma unroll
    for (int rt = 0; rt < 18; ++rt) wq[rt] = wqp[rt * 64];
    wqp += 18 * 64;
  }

#pragma unroll 1
  for (int oo = 0; oo < 4; ++oo) {
    const int o = og * 4 + oo;

    // phase 1: 18 MFMAs, predictor bias folded into C-operand.
    // lane holds pred fp32 for idx=c8*9+k (cin=kq*8+c8) at px: acc[idx>>2][idx&3]
    f32x4 acc[18];
    if (USE_WQ) {
#pragma unroll
      for (int rt = 0; rt < 18; ++rt) {
        const f32x4 bb = *(const f32x4*)&bp_s[oo * 288 + kq * 72 + rt * 4];
        acc[rt] = __builtin_amdgcn_mfma_f32_16x16x32_bf16(wq[rt], bfrag, bb, 0, 0, 0);
      }
      // prefetch next o's fragments; L2 latency hides under the norm phase
      if (oo < 3) {
#pragma unroll
        for (int rt = 0; rt < 18; ++rt) wq[rt] = wqp[rt * 64];
        wqp += 18 * 64;
      }
    } else {
      const float* ab = Wp + (o * 288 + (m16 >> 2) * 72 + (m16 & 3)) * 32 + kq * 8;
#pragma unroll
      for (int rt = 0; rt < 18; ++rt) {
        const float* ap = ab + rt * 4 * 32;
        float4 a0 = *(const float4*)ap;
        float4 a1 = *(const float4*)(ap + 4);
        union { short8 v; unsigned u[4]; } af;
        af.u[0] = f2bf_pk(a0.x, a0.y);
        af.u[1] = f2bf_pk(a0.z, a0.w);
        af.u[2] = f2bf_pk(a1.x, a1.y);
        af.u[3] = f2bf_pk(a1.z, a1.w);
        const f32x4 bb = *(const f32x4*)&bp_s[oo * 288 + kq * 72 + rt * 4];
        acc[rt] = __builtin_amdgcn_mfma_f32_16x16x32_bf16(af.v, bfrag, bb, 0, 0, 0);
      }
    }

    // cin-norm denominators: local partial + butterfly across kq (bits 4,5)
    float rinv[9];
#pragma unroll
    for (int kk = 0; kk < 9; ++kk) rinv[kk] = 0.f;
#pragma unroll
    for (int c8 = 0; c8 < 8; ++c8)
#pragma unroll
      for (int kk = 0; kk < 9; ++kk) {
        const int idx = c8 * 9 + kk;
        const float v = acc[idx >> 2][idx & 3];
        rinv[kk] += v * v;
      }
#pragma unroll
    for (int kk = 0; kk < 9; ++kk) {
      float s = rinv[kk];
      s += __shfl_xor(s, 16);
      s += __shfl_xor(s, 32);
      rinv[kk] = rsqrtf(fmaxf(s, 1e-24f));  // == 1/max(sqrt(s),1e-12)
    }

    // k-norm + contraction + dyn-bias partials: s2 and dot accumulated in
    // one pass (no tk[] storage); r2 applied to dot afterwards.
    const f32x4 wb0 = *(const f32x4*)&Wb_s[oo * 32 + kq * 8];
    const f32x4 wb1 = *(const f32x4*)&Wb_s[oo * 32 + kq * 8 + 4];
    float oacc = 0.f;
#pragma unroll
    for (int c8 = 0; c8 < 8; ++c8) {
      float s2 = 0.f, dot = 0.f;
#pragma unroll
      for (int kk = 0; kk < 9; ++kk) {
        const int idx = c8 * 9 + kk;
        const float tv = acc[idx >> 2][idx & 3] * rinv[kk];
        s2 += tv * tv;
        const float pv = (idx & 1) ? bfhi(patchp[idx >> 1]) : bflo(patchp[idx >> 1]);
        dot += tv * pv;
      }
      oacc += rsqrtf(fmaxf(s2, 1e-24f)) * dot;
      const int idc = c8 * 9 + 4;  // center tap for dyn bias
      const float xc = (idc & 1) ? bfhi(patchp[idc >> 1]) : bflo(patchp[idc >> 1]);
      const float wbv = (c8 < 4) ? ((const float*)&wb0)[c8] : ((const float*)&wb1)[c8 - 4];
      oacc += wbv * xc;
    }
    oacc += __shfl_xor(oacc, 16);
    oacc += __shfl_xor(oacc, 32);
    if (kq == 0)
      out[((b * 32 + o) * 64 + h) * 64 + px] = oacc + bias4[oo];
  }
}

extern "C" void kernel_launch(void* const* d_in, const int* in_sizes, int n_in,
                              void* d_out, int out_size, void* d_ws, size_t ws_size,
                              hipStream_t stream) {
  const float* x  = (const float*)d_in[0];
  const float* Wp = (const float*)d_in[1];
  const float* bp = (const float*)d_in[2];
  float* out = (float*)d_out;
  const size_t wq_bytes = (size_t)32 * 18 * 64 * 8 * 2;  // 589824
  if (ws_size >= wq_bytes) {
    prep_kernel<<<576, 256, 0, stream>>>(Wp, (unsigned*)d_ws);
    dppc6_kernel<true><<<1024, TPB, 0, stream>>>(x, Wp, bp, (const unsigned*)d_ws, out);
  } else {
    dppc6_kernel<false><<<1024, TPB, 0, stream>>>(x, Wp, bp, nullptr, out);
  }
}